// Round 2
// baseline (300.254 us; speedup 1.0000x reference)
//
#include <hip/hip_runtime.h>
#include <math.h>

static constexpr int B_  = 2;
static constexpr int S_  = 2048;
static constexpr int E_  = 1024;
static constexpr int NH_ = 4;
static constexpr int HD_ = 256;
static constexpr int BH_ = B_ * NH_;

typedef __attribute__((ext_vector_type(8))) _Float16 half8;
typedef __attribute__((ext_vector_type(4))) float    f32x4;
typedef __attribute__((ext_vector_type(4))) _Float16 half4v;

// ---------------- Kernel 1: gates + fp16 Q/K + V-transpose (R2: vectorized loads/stores) ----------------
__global__ __launch_bounds__(1024) void prep_kernel(
    const float* __restrict__ q, const float* __restrict__ k, const float* __restrict__ v,
    const float* __restrict__ igk, const float* __restrict__ igb,
    const float* __restrict__ fgk, const float* __restrict__ fgb,
    float* __restrict__ ig_out, float* __restrict__ fg_out,
    _Float16* __restrict__ Qh, _Float16* __restrict__ Kh, _Float16* __restrict__ Vt)
{
    __shared__ __align__(16) char PSM[98304];
    float4* wi = (float4*)PSM;          // [3072] 48 KB
    float4* wf = wi + 3 * E_;           // [3072] 48 KB

    const int t = threadIdx.x;
    #pragma unroll
    for (int i = 0; i < 3; ++i) {
        int e = t + 1024 * i;
        wi[e] = ((const float4*)igk)[e];
        wf[e] = ((const float4*)fgk)[e];
    }
    __syncthreads();

    const int wave = t >> 6;
    const int l    = t & 63;
    const int bs   = blockIdx.x * 16 + wave;     // b*S + s
    const int b = bs >> 11, s = bs & (S_ - 1);
    const float* qrow = q + (size_t)bs * E_;
    const float* krow = k + (size_t)bs * E_;
    const float* vrow = v + (size_t)bs * E_;

    float accI[4] = {0.f,0.f,0.f,0.f}, accF[4] = {0.f,0.f,0.f,0.f};
    #pragma unroll
    for (int j = 0; j < 12; ++j) {
        const int e4 = l * 4 + 256 * j;          // 4 consecutive elements of gate_in
        float4 g4;
        if (j < 4)       g4 = *(const float4*)(qrow + e4);
        else if (j < 8)  g4 = *(const float4*)(krow + (e4 - E_));
        else             g4 = *(const float4*)(vrow + (e4 - 2 * E_));
        const float ge[4] = {g4.x, g4.y, g4.z, g4.w};
        if (j < 4) {
            const int d = e4 & 255, hh = e4 >> 8;
            half4v st;
            st.x = (_Float16)(ge[0] * 0.0625f); st.y = (_Float16)(ge[1] * 0.0625f);
            st.z = (_Float16)(ge[2] * 0.0625f); st.w = (_Float16)(ge[3] * 0.0625f);
            *(half4v*)(Qh + (((size_t)(b * NH_ + hh)) * S_ + s) * HD_ + d) = st;
        } else if (j < 8) {
            const int e2 = e4 - E_;
            const int d = e2 & 255, hh = e2 >> 8;
            half4v st;
            st.x = (_Float16)ge[0]; st.y = (_Float16)ge[1];
            st.z = (_Float16)ge[2]; st.w = (_Float16)ge[3];
            *(half4v*)(Kh + (((size_t)(b * NH_ + hh)) * S_ + s) * HD_ + d) = st;
        }
        #pragma unroll
        for (int i = 0; i < 4; ++i) {
            float4 wiv = wi[e4 + i];
            float4 wfv = wf[e4 + i];
            accI[0] = fmaf(ge[i], wiv.x, accI[0]); accI[1] = fmaf(ge[i], wiv.y, accI[1]);
            accI[2] = fmaf(ge[i], wiv.z, accI[2]); accI[3] = fmaf(ge[i], wiv.w, accI[3]);
            accF[0] = fmaf(ge[i], wfv.x, accF[0]); accF[1] = fmaf(ge[i], wfv.y, accF[1]);
            accF[2] = fmaf(ge[i], wfv.z, accF[2]); accF[3] = fmaf(ge[i], wfv.w, accF[3]);
        }
    }
    #pragma unroll
    for (int m = 1; m < 64; m <<= 1) {
        #pragma unroll
        for (int h = 0; h < 4; ++h) {
            accI[h] += __shfl_xor(accI[h], m);
            accF[h] += __shfl_xor(accF[h], m);
        }
    }
    if (l == 0) {
        #pragma unroll
        for (int h = 0; h < 4; ++h) {
            ig_out[((size_t)(b * NH_ + h)) * S_ + s] = accI[h] + igb[h];
            fg_out[((size_t)(b * NH_ + h)) * S_ + s] = accF[h] + fgb[h];
        }
    }

    __syncthreads();    // all weight reads done; reuse LDS for transpose
    {
        float (*tile)[65] = (float(*)[65])(PSM + (t >> 8) * 16640);
        const int tid = t & 255;
        const int m  = blockIdx.x * 4 + (t >> 8);    // 0..1023
        const int bh = m & 7;
        const int sb = (m >> 3) & 31;
        const int db = m >> 8;
        const int bb = bh >> 2, hh = bh & 3;
        const int j4 = (tid & 15) * 4;
        const int i0 = tid >> 4;
        const float* src = v + ((size_t)(bb * S_ + sb * 64)) * E_ + hh * HD_ + db * 64;
        #pragma unroll
        for (int p = 0; p < 4; ++p) {
            int i = i0 + p * 16;
            float4 val = *(const float4*)(src + (size_t)i * E_ + j4);
            tile[i][j4] = val.x; tile[i][j4+1] = val.y; tile[i][j4+2] = val.z; tile[i][j4+3] = val.w;
        }
        __syncthreads();
        const int s4 = (tid & 15) * 4;
        const int d0 = tid >> 4;
        _Float16* dst = Vt + ((size_t)bh * HD_ + db * 64) * S_ + sb * 64;
        #pragma unroll
        for (int p = 0; p < 4; ++p) {
            int d = d0 + p * 16;
            half4v pk;
            pk.x = (_Float16)tile[s4][d];   pk.y = (_Float16)tile[s4+1][d];
            pk.z = (_Float16)tile[s4+2][d]; pk.w = (_Float16)tile[s4+3][d];
            *(half4v*)(dst + (size_t)d * S_ + s4) = pk;
        }
    }
}

// ---------------- Kernel 2 (R2): non-draining tile barrier + pass-split grid ----------------
// R1 post-mortem: __syncthreads() emits s_waitcnt vmcnt(0) before s_barrier, draining the
// K/V register prefetches every tile -> full L2 latency serialized, MfmaUtil 8%.
// Fix 1: main-loop barrier = lgkmcnt(0)-only (P ds_writes drained; global prefetches
//        stay in flight across the barrier; double-buffered P makes this race-free).
// Fix 2: split the {u, 63-u} pass pair into 2 blocks (grid 512 = 2 blocks/CU, 4 waves/SIMD)
//        for 2x TLP; in-order dispatch pairs short+long blocks of one head on each CU.
static constexpr int PB_BYTES = 32 * 128 * 2;          // one P buffer (8 KB)
static constexpr int OFF_AMM = 2 * PB_BYTES;           // 16384
static constexpr int OFF_G   = OFF_AMM + S_ * 4;       // 24576
static constexpr int OFF_M   = OFF_G + S_ * 4;         // 32768
static constexpr int OFF_RS  = OFF_M + S_ * 4;         // 40960
static constexpr int OFF_SS  = OFF_RS + 8 * 32 * 4;    // 41984
static constexpr int OFF_WR  = OFF_SS + 8 * 32 * 4;    // 43008
static constexpr int SMB     = OFF_WR + 64;            // 43072

__global__ __launch_bounds__(512, 4) void mlstm_kernel(
    const _Float16* __restrict__ Qh, const _Float16* __restrict__ Kh,
    const _Float16* __restrict__ Vt,
    const float* __restrict__ ig, const float* __restrict__ fg,
    const float* __restrict__ rms_scale, float* __restrict__ out)
{
    __shared__ __align__(16) char SMEM[SMB];
    char*  Pb    = SMEM;                             // [2][32][128] halfs, swizzled
    float* sAmM  = (float*)(SMEM + OFF_AMM);         // [S]
    float* sG    = (float*)(SMEM + OFF_G);           // [S]
    float* sM    = (float*)(SMEM + OFF_M);           // [S]
    float* rsumP = (float*)(SMEM + OFF_RS);          // [8][32]
    float* ssP   = (float*)(SMEM + OFF_SS);          // [8][32]
    float* wred  = (float*)(SMEM + OFF_WR);          // [8] + [8]
    float* wred2 = wred + 8;

    const int z  = blockIdx.x;
    const int bh = z & 7;                 // one head per XCD
    const int u  = (z >> 3) & 31;         // 0..31
    const int pass = z >> 8;              // 0 or 1 (split pair across 2 blocks)
    const int b  = bh >> 2, h = bh & 3;
    const int t  = threadIdx.x;
    const int w  = t >> 6;                // 0..7
    const int l  = t & 63;
    const int col  = l & 15;
    const int quad = l >> 4;
    const int qo   = quad * 8;

    // ---- scan prologue: wave-level shfl scans ----
    {
        const float* fgp = fg + (size_t)bh * S_;
        const float* igp = ig + (size_t)bh * S_;
        float4 fx = *(const float4*)(fgp + t * 4);
        float4 ix = *(const float4*)(igp + t * 4);
        float xi[4] = {fx.x, fx.y, fx.z, fx.w};
        float gi[4] = {ix.x, ix.y, ix.z, ix.w};
        float ls[4];
        float run = 0.f;
        #pragma unroll
        for (int i = 0; i < 4; ++i) {
            float x = xi[i];
            float lg = (x >= 0.f) ? -log1pf(expf(-x)) : (x - log1pf(expf(x)));
            run += lg;
            ls[i] = run;
        }
        const float own = run;
        #pragma unroll
        for (int m = 1; m < 64; m <<= 1) {
            float o = __shfl_up(run, m);
            if (l >= m) run += o;
        }
        if (l == 63) wred[w] = run;
        __syncthreads();
        float wpre = 0.f;
        for (int ww = 0; ww < w; ++ww) wpre += wred[ww];
        const float exclT = wpre + run - own;
        float A[4], g[4], gm[4];
        float rmax = -__builtin_inff();
        #pragma unroll
        for (int i = 0; i < 4; ++i) {
            A[i] = exclT + ls[i];
            g[i] = gi[i] - A[i];
            rmax = fmaxf(rmax, g[i]);
            gm[i] = rmax;
        }
        float sm = rmax;
        #pragma unroll
        for (int m = 1; m < 64; m <<= 1) {
            float o = __shfl_up(sm, m);
            if (l >= m) sm = fmaxf(sm, o);
        }
        if (l == 63) wred2[w] = sm;
        __syncthreads();
        float exm = -__builtin_inff();
        for (int ww = 0; ww < w; ++ww) exm = fmaxf(exm, wred2[ww]);
        float up = __shfl_up(sm, 1);
        if (l > 0) exm = fmaxf(exm, up);
        #pragma unroll
        for (int i = 0; i < 4; ++i) {
            float cm = fmaxf(exm, gm[i]);
            float Mi = A[i] + cm;
            sAmM[t * 4 + i] = A[i] - Mi;
            sG[t * 4 + i]   = g[i];
            sM[t * 4 + i]   = Mi;
        }
        __syncthreads();
    }

    const _Float16* Qp  = Qh + (size_t)bh * S_ * HD_;
    const _Float16* Kp  = Kh + (size_t)bh * S_ * HD_;
    const _Float16* Vtp = Vt + (size_t)bh * HD_ * S_;

    const float rsc0 = 1.f + rms_scale[w * 32 + col];
    const float rsc1 = 1.f + rms_scale[w * 32 + 16 + col];

    int buf = 0;

    const int rb = pass ? (63 - u) : u;
    const int rowbase = rb * 32;
    const int Tt = (rb >> 2) + 1;

    // Q fragments: both 16-row halves (64 VGPR), reused across all tiles
    half8 qf0[8], qf1[8];
    #pragma unroll
    for (int kk = 0; kk < 8; ++kk) {
        qf0[kk] = *(const half8*)(Qp + (size_t)(rowbase + col) * HD_ + kk * 32 + qo);
        qf1[kk] = *(const half8*)(Qp + (size_t)(rowbase + 16 + col) * HD_ + kk * 32 + qo);
    }
    float amM0[4], amM1[4];
    #pragma unroll
    for (int rr = 0; rr < 4; ++rr) {
        amM0[rr] = sAmM[rowbase + quad * 4 + rr];
        amM1[rr] = sAmM[rowbase + 16 + quad * 4 + rr];
    }

    f32x4 acc[4];
    #pragma unroll
    for (int i = 0; i < 4; ++i) acc[i] = (f32x4){0.f, 0.f, 0.f, 0.f};
    float rs0[4] = {0.f,0.f,0.f,0.f}, rs1[4] = {0.f,0.f,0.f,0.f};

    // K fragment prefetch for tile 0 (this wave's exclusive 16 K-rows)
    const _Float16* kcol_base = Kp + (size_t)(w * 16 + col) * HD_ + qo;
    half8 kf[8];
    #pragma unroll
    for (int kk = 0; kk < 8; ++kk)
        kf[kk] = *(const half8*)(kcol_base + kk * 32);

    half8 vf[8];
    for (int jt = 0; jt < Tt; ++jt) {
        const int c0 = jt << 7;
        // V fragments for THIS tile (consumed after the barrier -> long latency window)
        #pragma unroll
        for (int nsub = 0; nsub < 2; ++nsub) {
            #pragma unroll
            for (int kh = 0; kh < 4; ++kh)
                vf[nsub * 4 + kh] = *(const half8*)(Vtp
                    + (size_t)(w * 32 + nsub * 16 + col) * S_ + c0 + kh * 32 + qo);
        }
        // QK^T: 32 rows x this wave's 16 cols, K straight from L2
        f32x4 sc0 = (f32x4){0.f,0.f,0.f,0.f}, sc1 = (f32x4){0.f,0.f,0.f,0.f};
        #pragma unroll
        for (int kk = 0; kk < 8; ++kk) {
            sc0 = __builtin_amdgcn_mfma_f32_16x16x32_f16(qf0[kk], kf[kk], sc0, 0, 0, 0);
            sc1 = __builtin_amdgcn_mfma_f32_16x16x32_f16(qf1[kk], kf[kk], sc1, 0, 0, 0);
        }
        // K prefetch for next tile (covered by fixup + barrier + PV)
        if (jt + 1 < Tt) {
            const _Float16* kb = kcol_base + (size_t)(c0 + 128) * HD_;
            #pragma unroll
            for (int kk = 0; kk < 8; ++kk)
                kf[kk] = *(const half8*)(kb + kk * 32);
        }
        // fixup: p = s * exp(AmM[row] + G[col]), causal mask, fp16 -> swizzled P
        const int gcol = c0 + w * 16 + col;
        const float gv = sG[gcol];
        char* pbC = Pb + buf * PB_BYTES;
        const int hcb = (w * 16 + col) << 1;
        #pragma unroll
        for (int rr = 0; rr < 4; ++rr) {
            const int r0 = quad * 4 + rr;
            const int sw = (r0 & 7) << 4;
            float e0 = __expf(amM0[rr] + gv);
            float p0 = (gcol <= rowbase + r0) ? sc0[rr] * e0 : 0.f;
            rs0[rr] += p0;
            *(_Float16*)(pbC + (((r0 << 8) + hcb) ^ sw)) = (_Float16)p0;
            float e1 = __expf(amM1[rr] + gv);
            float p1 = (gcol <= rowbase + 16 + r0) ? sc1[rr] * e1 : 0.f;
            rs1[rr] += p1;
            const int r1 = r0 + 16;
            *(_Float16*)(pbC + (((r1 << 8) + hcb) ^ sw)) = (_Float16)p1;
        }
        // Non-draining barrier: drain only LDS ops (P writes); K/V global
        // prefetches stay in flight across the barrier (T4 counted-wait idea).
        asm volatile("s_waitcnt lgkmcnt(0)" ::: "memory");
        __builtin_amdgcn_s_barrier();
        // PV: A = P[32x128] from swizzled LDS, B = V^T n-slice (w*32..+32) from L2
        #pragma unroll
        for (int rsub = 0; rsub < 2; ++rsub) {
            const int prow = rsub * 16 + col;
            half8 af[4];
            #pragma unroll
            for (int kh = 0; kh < 4; ++kh)
                af[kh] = *(const half8*)(pbC
                    + ((prow << 8) + ((kh * 64 + qo * 2) ^ ((col & 7) << 4))));
            #pragma unroll
            for (int kh = 0; kh < 4; ++kh) {
                acc[rsub * 2 + 0] = __builtin_amdgcn_mfma_f32_16x16x32_f16(af[kh], vf[kh],     acc[rsub * 2 + 0], 0, 0, 0);
                acc[rsub * 2 + 1] = __builtin_amdgcn_mfma_f32_16x16x32_f16(af[kh], vf[4 + kh], acc[rsub * 2 + 1], 0, 0, 0);
            }
        }
        buf ^= 1;
    }

    // ---- epilogue: rowsum across 8 col-waves, normalize, RMSNorm, store slice ----
    #pragma unroll
    for (int m = 1; m < 16; m <<= 1) {
        #pragma unroll
        for (int rr = 0; rr < 4; ++rr) {
            rs0[rr] += __shfl_xor(rs0[rr], m);
            rs1[rr] += __shfl_xor(rs1[rr], m);
        }
    }
    if (col == 0) {
        #pragma unroll
        for (int rr = 0; rr < 4; ++rr) {
            rsumP[w * 32 + quad * 4 + rr]      = rs0[rr];
            rsumP[w * 32 + 16 + quad * 4 + rr] = rs1[rr];
        }
    }
    __syncthreads();
    float inv0[4], inv1[4];
    #pragma unroll
    for (int rr = 0; rr < 4; ++rr) {
        const int r0 = quad * 4 + rr;
        float tot0 = 0.f, tot1 = 0.f;
        #pragma unroll
        for (int ww = 0; ww < 8; ++ww) {
            tot0 += rsumP[ww * 32 + r0];
            tot1 += rsumP[ww * 32 + 16 + r0];
        }
        float M0 = sM[rowbase + r0];
        float M1 = sM[rowbase + 16 + r0];
        inv0[rr] = 1.0f / (fmaxf(tot0, __expf(-M0)) + 1e-6f);
        inv1[rr] = 1.0f / (fmaxf(tot1, __expf(-M1)) + 1e-6f);
    }
    float ss0[4] = {0.f,0.f,0.f,0.f}, ss1[4] = {0.f,0.f,0.f,0.f};
    #pragma unroll
    for (int nsub = 0; nsub < 2; ++nsub) {
        #pragma unroll
        for (int rr = 0; rr < 4; ++rr) {
            float h0 = acc[nsub][rr] * inv0[rr];
            acc[nsub][rr] = h0;
            ss0[rr] = fmaf(h0, h0, ss0[rr]);
            float h1 = acc[2 + nsub][rr] * inv1[rr];
            acc[2 + nsub][rr] = h1;
            ss1[rr] = fmaf(h1, h1, ss1[rr]);
        }
    }
    #pragma unroll
    for (int m = 1; m < 16; m <<= 1) {
        #pragma unroll
        for (int rr = 0; rr < 4; ++rr) {
            ss0[rr] += __shfl_xor(ss0[rr], m);
            ss1[rr] += __shfl_xor(ss1[rr], m);
        }
    }
    if (col == 0) {
        #pragma unroll
        for (int rr = 0; rr < 4; ++rr) {
            ssP[w * 32 + quad * 4 + rr]      = ss0[rr];
            ssP[w * 32 + 16 + quad * 4 + rr] = ss1[rr];
        }
    }
    __syncthreads();
    #pragma unroll
    for (int rr = 0; rr < 4; ++rr) {
        const int r0 = quad * 4 + rr;
        float sst0 = 0.f, sst1 = 0.f;
        #pragma unroll
        for (int ww = 0; ww < 8; ++ww) {
            sst0 += ssP[ww * 32 + r0];
            sst1 += ssP[ww * 32 + 16 + r0];
        }
        float rstd0 = rsqrtf(sst0 * (1.0f / HD_) + 1e-6f);
        float rstd1 = rsqrtf(sst1 * (1.0f / HD_) + 1e-6f);
        float* o0 = out + ((size_t)(b * S_ + rowbase + r0)) * E_ + h * HD_ + w * 32;
        float* o1 = out + ((size_t)(b * S_ + rowbase + 16 + r0)) * E_ + h * HD_ + w * 32;
        o0[col]      = acc[0][rr] * rstd0 * rsc0;
        o0[16 + col] = acc[1][rr] * rstd0 * rsc1;
        o1[col]      = acc[2][rr] * rstd1 * rsc0;
        o1[16 + col] = acc[3][rr] * rstd1 * rsc1;
    }
}

extern "C" void kernel_launch(void* const* d_in, const int* in_sizes, int n_in,
                              void* d_out, int out_size, void* d_ws, size_t ws_size,
                              hipStream_t stream) {
    (void)in_sizes; (void)n_in; (void)out_size; (void)ws_size;
    const float* q   = (const float*)d_in[0];
    const float* k   = (const float*)d_in[1];
    const float* v   = (const float*)d_in[2];
    const float* igk = (const float*)d_in[3];
    const float* igb = (const float*)d_in[4];
    const float* fgk = (const float*)d_in[5];
    const float* fgb = (const float*)d_in[6];
    const float* rsc = (const float*)d_in[7];
    float* out = (float*)d_out;

    float* ws  = (float*)d_ws;
    float* ig  = ws;                          // BH*S each
    float* fg  = ws + (size_t)BH_ * S_;
    _Float16* Qh = (_Float16*)(ws + (size_t)2 * BH_ * S_);
    _Float16* Kh = Qh + (size_t)BH_ * S_ * HD_;
    _Float16* Vt = Kh + (size_t)BH_ * S_ * HD_;

    prep_kernel<<<B_ * S_ / 16, 1024, 0, stream>>>(q, k, v, igk, igb, fgk, fgb,
                                                   ig, fg, Qh, Kh, Vt);
    mlstm_kernel<<<BH_ * 64, 512, 0, stream>>>(Qh, Kh, Vt, ig, fg, rsc, out);
}

// Round 3
// 167.526 us; speedup vs baseline: 1.7923x; 1.7923x over previous
//
#include <hip/hip_runtime.h>
#include <math.h>

static constexpr int B_  = 2;
static constexpr int S_  = 2048;
static constexpr int E_  = 1024;
static constexpr int NH_ = 4;
static constexpr int HD_ = 256;
static constexpr int BH_ = B_ * NH_;

typedef __attribute__((ext_vector_type(8))) _Float16 half8;
typedef __attribute__((ext_vector_type(4))) float    f32x4;
typedef __attribute__((ext_vector_type(4))) _Float16 half4v;

// Fragment-major layouts (written by prep, read by mlstm as coalesced 1 KB lines):
//  Q/K per bh: frag(rb16 = s>>4, kk = d>>5) at ((rb16*8 + kk)*512) halfs;
//              lane l = (s&15) + (((d&31)>>3)<<4) holds halfs j = d&7.
//  V^T per bh: frag(ktile = s>>6, dblk = d>>4, kb = (s&63)>>5) at
//              (((ktile*16 + dblk)*2 + kb)*512) halfs; lane l = (d&15) + (((s&31)>>3)<<4), j = s&7.

// ---------------- Kernel 1: gates + fp16 Q/K (frag-major) + V frag-transpose ----------------
__global__ __launch_bounds__(1024) void prep_kernel(
    const float* __restrict__ q, const float* __restrict__ k, const float* __restrict__ v,
    const float* __restrict__ igk, const float* __restrict__ igb,
    const float* __restrict__ fgk, const float* __restrict__ fgb,
    float* __restrict__ ig_out, float* __restrict__ fg_out,
    _Float16* __restrict__ Qh, _Float16* __restrict__ Kh, _Float16* __restrict__ Vt)
{
    __shared__ __align__(16) char PSM[98304];
    float4* wi = (float4*)PSM;          // [3072] 48 KB
    float4* wf = wi + 3 * E_;           // [3072] 48 KB

    const int t = threadIdx.x;
    #pragma unroll
    for (int i = 0; i < 3; ++i) {
        int e = t + 1024 * i;
        wi[e] = ((const float4*)igk)[e];
        wf[e] = ((const float4*)fgk)[e];
    }
    __syncthreads();

    const int wave = t >> 6;
    const int l    = t & 63;
    const int bs   = blockIdx.x * 16 + wave;     // b*S + s
    const int b = bs >> 11, s = bs & (S_ - 1);
    const float* qrow = q + (size_t)bs * E_;
    const float* krow = k + (size_t)bs * E_;
    const float* vrow = v + (size_t)bs * E_;

    float accI[4] = {0.f,0.f,0.f,0.f}, accF[4] = {0.f,0.f,0.f,0.f};
    #pragma unroll
    for (int j = 0; j < 12; ++j) {
        const int e4 = l * 4 + 256 * j;          // 4 consecutive elements of gate_in
        float4 g4;
        if (j < 4)       g4 = *(const float4*)(qrow + e4);
        else if (j < 8)  g4 = *(const float4*)(krow + (e4 - E_));
        else             g4 = *(const float4*)(vrow + (e4 - 2 * E_));
        const float ge[4] = {g4.x, g4.y, g4.z, g4.w};
        if (j < 4) {
            const int d = e4 & 255, hh = e4 >> 8;
            // fragment-major store (d..d+3 stay within one 8-half group since d%4==0)
            const int idx = ((s >> 4) * 8 + (d >> 5)) * 512
                          + (s & 15) * 8 + (((d & 31) >> 3) << 7) + (d & 7);
            half4v st;
            st.x = (_Float16)(ge[0] * 0.0625f); st.y = (_Float16)(ge[1] * 0.0625f);
            st.z = (_Float16)(ge[2] * 0.0625f); st.w = (_Float16)(ge[3] * 0.0625f);
            *(half4v*)(Qh + ((size_t)(b * NH_ + hh)) * (S_ * HD_) + idx) = st;
        } else if (j < 8) {
            const int e2 = e4 - E_;
            const int d = e2 & 255, hh = e2 >> 8;
            const int idx = ((s >> 4) * 8 + (d >> 5)) * 512
                          + (s & 15) * 8 + (((d & 31) >> 3) << 7) + (d & 7);
            half4v st;
            st.x = (_Float16)ge[0]; st.y = (_Float16)ge[1];
            st.z = (_Float16)ge[2]; st.w = (_Float16)ge[3];
            *(half4v*)(Kh + ((size_t)(b * NH_ + hh)) * (S_ * HD_) + idx) = st;
        }
        #pragma unroll
        for (int i = 0; i < 4; ++i) {
            float4 wiv = wi[e4 + i];
            float4 wfv = wf[e4 + i];
            accI[0] = fmaf(ge[i], wiv.x, accI[0]); accI[1] = fmaf(ge[i], wiv.y, accI[1]);
            accI[2] = fmaf(ge[i], wiv.z, accI[2]); accI[3] = fmaf(ge[i], wiv.w, accI[3]);
            accF[0] = fmaf(ge[i], wfv.x, accF[0]); accF[1] = fmaf(ge[i], wfv.y, accF[1]);
            accF[2] = fmaf(ge[i], wfv.z, accF[2]); accF[3] = fmaf(ge[i], wfv.w, accF[3]);
        }
    }
    #pragma unroll
    for (int m = 1; m < 64; m <<= 1) {
        #pragma unroll
        for (int h = 0; h < 4; ++h) {
            accI[h] += __shfl_xor(accI[h], m);
            accF[h] += __shfl_xor(accF[h], m);
        }
    }
    if (l == 0) {
        #pragma unroll
        for (int h = 0; h < 4; ++h) {
            ig_out[((size_t)(b * NH_ + h)) * S_ + s] = accI[h] + igb[h];
            fg_out[((size_t)(b * NH_ + h)) * S_ + s] = accF[h] + fgb[h];
        }
    }

    __syncthreads();    // all weight reads done; reuse LDS for V transpose
    {
        float (*tile)[65] = (float(*)[65])(PSM + (t >> 8) * 16640);
        const int tid = t & 255;
        const int m  = blockIdx.x * 4 + (t >> 8);    // 0..1023 tile jobs
        const int bh = m & 7;
        const int sb = (m >> 3) & 31;                // ktile
        const int db = m >> 8;                       // d block of 64
        const int bb = bh >> 2, hh = bh & 3;
        const int j4 = (tid & 15) * 4;
        const int i0 = tid >> 4;
        const float* src = v + ((size_t)(bb * S_ + sb * 64)) * E_ + hh * HD_ + db * 64;
        #pragma unroll
        for (int p = 0; p < 4; ++p) {
            int i = i0 + p * 16;
            float4 val = *(const float4*)(src + (size_t)i * E_ + j4);
            tile[i][j4] = val.x; tile[i][j4+1] = val.y; tile[i][j4+2] = val.z; tile[i][j4+3] = val.w;
        }
        __syncthreads();
        // emit V^T fragments: sub-wave sw = dblk_local, 2 kb frags each, coalesced 1 KB stores
        const int ll = tid & 63;
        const int sw_ = tid >> 6;
        _Float16* dstb = Vt + (size_t)bh * (S_ * HD_);
        #pragma unroll
        for (int kb = 0; kb < 2; ++kb) {
            half8 pk;
            #pragma unroll
            for (int jj = 0; jj < 8; ++jj)
                pk[jj] = (_Float16)tile[kb * 32 + (ll >> 4) * 8 + jj][sw_ * 16 + (ll & 15)];
            *(half8*)(dstb + ((size_t)((sb * 16 + db * 4 + sw_) * 2 + kb)) * 512 + ll * 8) = pk;
        }
    }
}

// ---------------- Kernel 2 (R3): frag-major direct-L2 K/V, P-only LDS, reg dbuf ----------------
// R2 post-mortem: launch_bounds(512,4) capped regs at 128 -> spills -> 442 MB scratch traffic.
// R1 model fix: direct-L2 frag loads were 512B-strided (16 lines / b128) -> L2-transaction-bound.
// R3: prep writes Q/K/V in fragment-major order so every kf/vf load is one contiguous,
// coalesced 1 KB line from the per-XCD L2 (head stays resident; bh = z&7 pins the XCD).
// No K/V LDS staging at all; K/V frags double-buffered in regs, issued a full tile ahead;
// the per-tile barrier is lgkm-only so those loads stay in flight across it.
static constexpr int OFF_AMM = 8192;                   // P: [2][32][128B] swizzled at 0
static constexpr int OFF_G   = OFF_AMM + S_ * 4;
static constexpr int OFF_M   = OFF_G + S_ * 4;
static constexpr int OFF_RS  = OFF_M + S_ * 4;         // [128] floats
static constexpr int OFF_SS  = OFF_RS + 512;
static constexpr int OFF_WR  = OFF_SS + 512;
static constexpr int SMB     = OFF_WR + 64;

#define TILE_BODY(KFC, VFC, KFN, VFN)                                         \
{                                                                             \
    const int jtn = jt + 1;                                                   \
    if (jtn < Tt) {                                                           \
        const _Float16* kb_ = Kp + ((size_t)((jtn * 4 + cq) * 8)) * 512 + l * 8; \
        _Pragma("unroll")                                                     \
        for (int kk = 0; kk < 8; ++kk)                                        \
            KFN[kk] = *(const half8*)(kb_ + kk * 512);                        \
        const _Float16* vb_ = Vtp + ((size_t)(jtn * 32)) * 512 + l * 8;       \
        _Pragma("unroll")                                                     \
        for (int nn = 0; nn < 4; ++nn) {                                      \
            _Pragma("unroll")                                                 \
            for (int kb = 0; kb < 2; ++kb)                                    \
                VFN[nn * 2 + kb] = *(const half8*)(vb_ + ((cq * 4 + nn) * 2 + kb) * 512); \
        }                                                                     \
    }                                                                         \
    f32x4 sc_ = (f32x4){0.f, 0.f, 0.f, 0.f};                                  \
    _Pragma("unroll")                                                         \
    for (int kk = 0; kk < 8; ++kk)                                            \
        sc_ = __builtin_amdgcn_mfma_f32_16x16x32_f16(qf[kk], KFC[kk], sc_, 0, 0, 0); \
    const int gcol = jt * 64 + cq * 16 + col;                                 \
    const float gv = sG[gcol];                                                \
    char* pbC = Pb + buf * 4096;                                              \
    _Pragma("unroll")                                                         \
    for (int rr = 0; rr < 4; ++rr) {                                          \
        const int prow = rw * 16 + quad * 4 + rr;                             \
        float e_ = __expf(amM[rr] + gv);                                      \
        float p_ = (gcol <= rowbase + prow) ? sc_[rr] * e_ : 0.f;             \
        rs[rr] += p_;                                                         \
        *(_Float16*)(pbC + prow * 128 + (((cq * 16 + col) * 2) ^ ((prow & 7) << 4))) = (_Float16)p_; \
    }                                                                         \
    asm volatile("s_waitcnt lgkmcnt(0)" ::: "memory");                        \
    __builtin_amdgcn_s_barrier();                                             \
    _Pragma("unroll")                                                         \
    for (int kb = 0; kb < 2; ++kb) {                                          \
        half8 af_ = *(const half8*)(pbC + (rw * 16 + col) * 128 + ((kb * 64 + quad * 16) ^ ((col & 7) << 4))); \
        _Pragma("unroll")                                                     \
        for (int nn = 0; nn < 4; ++nn)                                        \
            acc[nn] = __builtin_amdgcn_mfma_f32_16x16x32_f16(af_, VFC[nn * 2 + kb], acc[nn], 0, 0, 0); \
    }                                                                         \
    buf ^= 1;                                                                 \
}

__global__ __launch_bounds__(512, 2) void mlstm_kernel(
    const _Float16* __restrict__ Qh, const _Float16* __restrict__ Kh,
    const _Float16* __restrict__ Vt,
    const float* __restrict__ ig, const float* __restrict__ fg,
    const float* __restrict__ rms_scale, float* __restrict__ out)
{
    __shared__ __align__(16) char SMEM[SMB];
    char*  Pb    = SMEM;                             // [2][32][64] halfs, swizzled
    float* sAmM  = (float*)(SMEM + OFF_AMM);         // [S]
    float* sG    = (float*)(SMEM + OFF_G);           // [S]
    float* sM    = (float*)(SMEM + OFF_M);           // [S]
    float* rsumP = (float*)(SMEM + OFF_RS);          // [2 rw][4 cq][16]
    float* ssP   = (float*)(SMEM + OFF_SS);
    float* wred  = (float*)(SMEM + OFF_WR);
    float* wred2 = wred + 8;

    const int z  = blockIdx.x;
    const int bh = z & 7;                 // one head per XCD
    const int u  = (z >> 3) & 31;
    const int pass = z >> 8;              // {u, 63-u} split across 2 blocks
    const int b  = bh >> 2, h = bh & 3;
    const int t  = threadIdx.x;
    const int w  = t >> 6;
    const int l  = t & 63;
    const int col  = l & 15;
    const int quad = l >> 4;
    const int rw   = w >> 2;              // row half (16 of 32 rows)
    const int cq   = w & 3;               // col/d quarter

    // ---- scan prologue: wave-level shfl scans ----
    {
        const float* fgp = fg + (size_t)bh * S_;
        const float* igp = ig + (size_t)bh * S_;
        float4 fx = *(const float4*)(fgp + t * 4);
        float4 ix = *(const float4*)(igp + t * 4);
        float xi[4] = {fx.x, fx.y, fx.z, fx.w};
        float gi[4] = {ix.x, ix.y, ix.z, ix.w};
        float ls[4];
        float run = 0.f;
        #pragma unroll
        for (int i = 0; i < 4; ++i) {
            float x = xi[i];
            float lg = (x >= 0.f) ? -log1pf(expf(-x)) : (x - log1pf(expf(x)));
            run += lg;
            ls[i] = run;
        }
        const float own = run;
        #pragma unroll
        for (int m = 1; m < 64; m <<= 1) {
            float o = __shfl_up(run, m);
            if (l >= m) run += o;
        }
        if (l == 63) wred[w] = run;
        __syncthreads();
        float wpre = 0.f;
        for (int ww = 0; ww < w; ++ww) wpre += wred[ww];
        const float exclT = wpre + run - own;
        float A[4], g[4], gm[4];
        float rmax = -__builtin_inff();
        #pragma unroll
        for (int i = 0; i < 4; ++i) {
            A[i] = exclT + ls[i];
            g[i] = gi[i] - A[i];
            rmax = fmaxf(rmax, g[i]);
            gm[i] = rmax;
        }
        float sm = rmax;
        #pragma unroll
        for (int m = 1; m < 64; m <<= 1) {
            float o = __shfl_up(sm, m);
            if (l >= m) sm = fmaxf(sm, o);
        }
        if (l == 63) wred2[w] = sm;
        __syncthreads();
        float exm = -__builtin_inff();
        for (int ww = 0; ww < w; ++ww) exm = fmaxf(exm, wred2[ww]);
        float up = __shfl_up(sm, 1);
        if (l > 0) exm = fmaxf(exm, up);
        #pragma unroll
        for (int i = 0; i < 4; ++i) {
            float cm = fmaxf(exm, gm[i]);
            float Mi = A[i] + cm;
            sAmM[t * 4 + i] = A[i] - Mi;
            sG[t * 4 + i]   = g[i];
            sM[t * 4 + i]   = Mi;
        }
        __syncthreads();
    }

    const _Float16* Qp  = Qh + (size_t)bh * S_ * HD_;
    const _Float16* Kp  = Kh + (size_t)bh * S_ * HD_;
    const _Float16* Vtp = Vt + (size_t)bh * HD_ * S_;

    const int rb = pass ? (63 - u) : u;
    const int rowbase = rb * 32;
    const int Tt = (rb >> 1) + 1;          // KVBLK=64 causal tile count

    // Q fragments for this wave's 16 rows (coalesced frag-major loads)
    half8 qf[8];
    {
        const _Float16* qb_ = Qp + ((size_t)(((rowbase >> 4) + rw) * 8)) * 512 + l * 8;
        #pragma unroll
        for (int kk = 0; kk < 8; ++kk)
            qf[kk] = *(const half8*)(qb_ + kk * 512);
    }
    float amM[4];
    #pragma unroll
    for (int rr = 0; rr < 4; ++rr)
        amM[rr] = sAmM[rowbase + rw * 16 + quad * 4 + rr];

    f32x4 acc[4];
    #pragma unroll
    for (int i = 0; i < 4; ++i) acc[i] = (f32x4){0.f, 0.f, 0.f, 0.f};
    float rs[4] = {0.f, 0.f, 0.f, 0.f};

    // preload tile 0 into set 0
    half8 kf0[8], vf0[8], kf1[8], vf1[8];
    {
        const _Float16* kb_ = Kp + ((size_t)(cq * 8)) * 512 + l * 8;
        #pragma unroll
        for (int kk = 0; kk < 8; ++kk)
            kf0[kk] = *(const half8*)(kb_ + kk * 512);
        const _Float16* vb_ = Vtp + l * 8;
        #pragma unroll
        for (int nn = 0; nn < 4; ++nn) {
            #pragma unroll
            for (int kb = 0; kb < 2; ++kb)
                vf0[nn * 2 + kb] = *(const half8*)(vb_ + ((cq * 4 + nn) * 2 + kb) * 512);
        }
    }

    int buf = 0;
    int jt = 0;
    while (true) {
        TILE_BODY(kf0, vf0, kf1, vf1);
        if (++jt >= Tt) break;
        TILE_BODY(kf1, vf1, kf0, vf0);
        if (++jt >= Tt) break;
    }

    // ---- epilogue: rowsum across 4 cq waves, normalize, RMSNorm, store slice ----
    #pragma unroll
    for (int m = 1; m < 16; m <<= 1) {
        #pragma unroll
        for (int rr = 0; rr < 4; ++rr) rs[rr] += __shfl_xor(rs[rr], m);
    }
    if (col == 0) {
        #pragma unroll
        for (int rr = 0; rr < 4; ++rr)
            rsumP[rw * 64 + cq * 16 + quad * 4 + rr] = rs[rr];
    }
    __syncthreads();
    float inv[4], ssv[4];
    #pragma unroll
    for (int rr = 0; rr < 4; ++rr) {
        const int r = quad * 4 + rr;
        float tot = rsumP[rw * 64 + r] + rsumP[rw * 64 + 16 + r]
                  + rsumP[rw * 64 + 32 + r] + rsumP[rw * 64 + 48 + r];
        float Mv = sM[rowbase + rw * 16 + r];
        inv[rr] = 1.0f / (fmaxf(tot, __expf(-Mv)) + 1e-6f);
        ssv[rr] = 0.f;
    }
    #pragma unroll
    for (int nn = 0; nn < 4; ++nn) {
        #pragma unroll
        for (int rr = 0; rr < 4; ++rr) {
            float hv = acc[nn][rr] * inv[rr];
            acc[nn][rr] = hv;
            ssv[rr] = fmaf(hv, hv, ssv[rr]);
        }
    }
    #pragma unroll
    for (int m = 1; m < 16; m <<= 1) {
        #pragma unroll
        for (int rr = 0; rr < 4; ++rr) ssv[rr] += __shfl_xor(ssv[rr], m);
    }
    if (col == 0) {
        #pragma unroll
        for (int rr = 0; rr < 4; ++rr)
            ssP[rw * 64 + cq * 16 + quad * 4 + rr] = ssv[rr];
    }
    __syncthreads();
    float rscv[4];
    #pragma unroll
    for (int nn = 0; nn < 4; ++nn)
        rscv[nn] = 1.0f + rms_scale[cq * 64 + nn * 16 + col];
    #pragma unroll
    for (int rr = 0; rr < 4; ++rr) {
        const int r = quad * 4 + rr;
        float sst = ssP[rw * 64 + r] + ssP[rw * 64 + 16 + r]
                  + ssP[rw * 64 + 32 + r] + ssP[rw * 64 + 48 + r];
        float rstd = rsqrtf(sst * (1.0f / HD_) + 1e-6f);
        const int rowg = rowbase + rw * 16 + r;
        float* orow = out + ((size_t)(b * S_ + rowg)) * E_ + h * HD_;
        #pragma unroll
        for (int nn = 0; nn < 4; ++nn)
            orow[cq * 64 + nn * 16 + col] = acc[nn][rr] * rstd * rscv[nn];
    }
}

extern "C" void kernel_launch(void* const* d_in, const int* in_sizes, int n_in,
                              void* d_out, int out_size, void* d_ws, size_t ws_size,
                              hipStream_t stream) {
    (void)in_sizes; (void)n_in; (void)out_size; (void)ws_size;
    const float* q   = (const float*)d_in[0];
    const float* k   = (const float*)d_in[1];
    const float* v   = (const float*)d_in[2];
    const float* igk = (const float*)d_in[3];
    const float* igb = (const float*)d_in[4];
    const float* fgk = (const float*)d_in[5];
    const float* fgb = (const float*)d_in[6];
    const float* rsc = (const float*)d_in[7];
    float* out = (float*)d_out;

    float* ws  = (float*)d_ws;
    float* ig  = ws;                          // BH*S each
    float* fg  = ws + (size_t)BH_ * S_;
    _Float16* Qh = (_Float16*)(ws + (size_t)2 * BH_ * S_);
    _Float16* Kh = Qh + (size_t)BH_ * S_ * HD_;
    _Float16* Vt = Kh + (size_t)BH_ * S_ * HD_;

    prep_kernel<<<B_ * S_ / 16, 1024, 0, stream>>>(q, k, v, igk, igb, fgk, fgb,
                                                   ig, fg, Qh, Kh, Vt);
    mlstm_kernel<<<BH_ * 64, 512, 0, stream>>>(Qh, Kh, Vt, ig, fg, rsc, out);
}

// Round 4
// 161.119 us; speedup vs baseline: 1.8636x; 1.0398x over previous
//
#include <hip/hip_runtime.h>
#include <math.h>

static constexpr int B_  = 2;
static constexpr int S_  = 2048;
static constexpr int E_  = 1024;
static constexpr int NH_ = 4;
static constexpr int HD_ = 256;
static constexpr int BH_ = B_ * NH_;

typedef __attribute__((ext_vector_type(8))) _Float16 half8;
typedef __attribute__((ext_vector_type(4))) float    f32x4;
typedef __attribute__((ext_vector_type(4))) _Float16 half4v;

// Fragment-major layouts (written by prep, read by mlstm as coalesced 1 KB lines):
//  Q/K per bh: frag(rb16 = s>>4, kk = d>>5) at ((rb16*8 + kk)*512) halfs;
//              lane l = (s&15) + (((d&31)>>3)<<4) holds halfs j = d&7.
//  V^T per bh: frag(ktile = s>>6, dblk = d>>4, kb = (s&63)>>5) at
//              (((ktile*16 + dblk)*2 + kb)*512) halfs; lane l = (d&15) + (((s&31)>>3)<<4), j = s&7.

// Swizzled LDS offset for the gate-weight float4 array: XOR bits 4-6 with e's
// bits 3-5 (16 B granule). R3's linear layout put lane stride at 64 B -> only 8
// banks live per b128 (32-way conflict); this spreads 8 distinct dwords/bank = free.
__device__ __forceinline__ int wofs(int e) { return (e << 4) ^ ((e & 0x38) << 1); }

// ---------------- Kernel 1: gates + fp16 Q/K (frag-major) + V frag-transpose ----------------
__global__ __launch_bounds__(1024) void prep_kernel(
    const float* __restrict__ q, const float* __restrict__ k, const float* __restrict__ v,
    const float* __restrict__ igk, const float* __restrict__ igb,
    const float* __restrict__ fgk, const float* __restrict__ fgb,
    float* __restrict__ ig_out, float* __restrict__ fg_out,
    _Float16* __restrict__ Qh, _Float16* __restrict__ Kh, _Float16* __restrict__ Vt)
{
    __shared__ __align__(16) char PSM[98304];
    char* wiB = PSM;            // 48 KB, swizzled float4 per element
    char* wfB = PSM + 49152;

    const int t = threadIdx.x;
    #pragma unroll
    for (int i = 0; i < 3; ++i) {
        int e = t + 1024 * i;
        *(float4*)(wiB + wofs(e)) = ((const float4*)igk)[e];
        *(float4*)(wfB + wofs(e)) = ((const float4*)fgk)[e];
    }
    __syncthreads();

    const int wave = t >> 6;
    const int l    = t & 63;
    const int bs   = blockIdx.x * 16 + wave;     // b*S + s
    const int b = bs >> 11, s = bs & (S_ - 1);
    const float* qrow = q + (size_t)bs * E_;
    const float* krow = k + (size_t)bs * E_;
    const float* vrow = v + (size_t)bs * E_;

    float accI[4] = {0.f,0.f,0.f,0.f}, accF[4] = {0.f,0.f,0.f,0.f};
    #pragma unroll
    for (int j = 0; j < 12; ++j) {
        const int e4 = l * 4 + 256 * j;          // 4 consecutive elements of gate_in
        float4 g4;
        if (j < 4)       g4 = *(const float4*)(qrow + e4);
        else if (j < 8)  g4 = *(const float4*)(krow + (e4 - E_));
        else             g4 = *(const float4*)(vrow + (e4 - 2 * E_));
        const float ge[4] = {g4.x, g4.y, g4.z, g4.w};
        if (j < 4) {
            const int d = e4 & 255, hh = e4 >> 8;
            const int idx = ((s >> 4) * 8 + (d >> 5)) * 512
                          + (s & 15) * 8 + (((d & 31) >> 3) << 7) + (d & 7);
            half4v st;
            st.x = (_Float16)(ge[0] * 0.0625f); st.y = (_Float16)(ge[1] * 0.0625f);
            st.z = (_Float16)(ge[2] * 0.0625f); st.w = (_Float16)(ge[3] * 0.0625f);
            *(half4v*)(Qh + ((size_t)(b * NH_ + hh)) * (S_ * HD_) + idx) = st;
        } else if (j < 8) {
            const int e2 = e4 - E_;
            const int d = e2 & 255, hh = e2 >> 8;
            const int idx = ((s >> 4) * 8 + (d >> 5)) * 512
                          + (s & 15) * 8 + (((d & 31) >> 3) << 7) + (d & 7);
            half4v st;
            st.x = (_Float16)ge[0]; st.y = (_Float16)ge[1];
            st.z = (_Float16)ge[2]; st.w = (_Float16)ge[3];
            *(half4v*)(Kh + ((size_t)(b * NH_ + hh)) * (S_ * HD_) + idx) = st;
        }
        #pragma unroll
        for (int i = 0; i < 4; ++i) {
            float4 wiv = *(const float4*)(wiB + wofs(e4 + i));
            float4 wfv = *(const float4*)(wfB + wofs(e4 + i));
            accI[0] = fmaf(ge[i], wiv.x, accI[0]); accI[1] = fmaf(ge[i], wiv.y, accI[1]);
            accI[2] = fmaf(ge[i], wiv.z, accI[2]); accI[3] = fmaf(ge[i], wiv.w, accI[3]);
            accF[0] = fmaf(ge[i], wfv.x, accF[0]); accF[1] = fmaf(ge[i], wfv.y, accF[1]);
            accF[2] = fmaf(ge[i], wfv.z, accF[2]); accF[3] = fmaf(ge[i], wfv.w, accF[3]);
        }
    }
    #pragma unroll
    for (int m = 1; m < 64; m <<= 1) {
        #pragma unroll
        for (int h = 0; h < 4; ++h) {
            accI[h] += __shfl_xor(accI[h], m);
            accF[h] += __shfl_xor(accF[h], m);
        }
    }
    if (l == 0) {
        #pragma unroll
        for (int h = 0; h < 4; ++h) {
            ig_out[((size_t)(b * NH_ + h)) * S_ + s] = accI[h] + igb[h];
            fg_out[((size_t)(b * NH_ + h)) * S_ + s] = accF[h] + fgb[h];
        }
    }

    __syncthreads();    // all weight reads done; reuse LDS for V transpose
    {
        float (*tile)[65] = (float(*)[65])(PSM + (t >> 8) * 16640);
        const int tid = t & 255;
        const int m  = blockIdx.x * 4 + (t >> 8);    // 0..1023 tile jobs
        const int bh = m & 7;
        const int sb = (m >> 3) & 31;                // ktile
        const int db = m >> 8;                       // d block of 64
        const int bb = bh >> 2, hh = bh & 3;
        const int j4 = (tid & 15) * 4;
        const int i0 = tid >> 4;
        const float* src = v + ((size_t)(bb * S_ + sb * 64)) * E_ + hh * HD_ + db * 64;
        #pragma unroll
        for (int p = 0; p < 4; ++p) {
            int i = i0 + p * 16;
            float4 val = *(const float4*)(src + (size_t)i * E_ + j4);
            tile[i][j4] = val.x; tile[i][j4+1] = val.y; tile[i][j4+2] = val.z; tile[i][j4+3] = val.w;
        }
        __syncthreads();
        const int ll = tid & 63;
        const int sw_ = tid >> 6;
        _Float16* dstb = Vt + (size_t)bh * (S_ * HD_);
        #pragma unroll
        for (int kb = 0; kb < 2; ++kb) {
            half8 pk;
            #pragma unroll
            for (int jj = 0; jj < 8; ++jj)
                pk[jj] = (_Float16)tile[kb * 32 + (ll >> 4) * 8 + jj][sw_ * 16 + (ll & 15)];
            *(half8*)(dstb + ((size_t)((sb * 16 + db * 4 + sw_) * 2 + kb)) * 512 + ll * 8) = pk;
        }
    }
}

// ---------------- Kernel 2 (R4): KVBLK=128, zero-duplication wave decomposition ----------------
// R3 post-mortem: correct + fast, but wave (rw,cq) duplicated its K/V quarter across the
// two rw halves -> 2x L2 traffic (=~32 of the 61 us). R4: 8 waves own DISJOINT 16-col K
// groups (QK) and DISJOINT 32-wide d-slices (PV); each wave holds both 16-row Q halves.
// KVBLK 128 halves barrier count; K/V loads have zero redundancy -> L2 floor ~17 us.
// K dbuf in regs (issued a tile ahead); V single-buffered but issued at tile top, consumed
// after the lgkm-only barrier; P [2][32][256B] swizzled is the only cross-wave traffic.
static constexpr int OFF_AMM = 16384;                  // P dbuf [2][32 rows][256 B]
static constexpr int OFF_G   = OFF_AMM + S_ * 4;       // 24576
static constexpr int OFF_M   = OFF_G + S_ * 4;         // 32768
static constexpr int OFF_RS  = OFF_M + S_ * 4;         // 40960: [8][32] floats
static constexpr int OFF_SS  = OFF_RS + 1024;          // 41984
static constexpr int OFF_WR  = OFF_SS + 1024;          // 43008
static constexpr int SMB     = OFF_WR + 64;            // 43072

#define TILE_BODY(KFC, KFN)                                                   \
{                                                                             \
    /* V fragments for THIS tile (consumed after the barrier) */              \
    const _Float16* vb_ = Vtp + (size_t)jt * 32768 + l * 8;                   \
    _Pragma("unroll")                                                         \
    for (int dn = 0; dn < 2; ++dn) {                                          \
        _Pragma("unroll")                                                     \
        for (int k0 = 0; k0 < 4; ++k0)                                        \
            vf[dn * 4 + k0] = *(const half8*)(vb_                             \
                + (((k0 >> 1) * 16 + w * 2 + dn) * 2 + (k0 & 1)) * 512);      \
    }                                                                         \
    /* K fragments for NEXT tile (stay in flight across the barrier) */       \
    if (jt + 1 < Tt) {                                                        \
        const _Float16* kb_ = Kp + ((size_t)((jt + 1) * 8 + w) * 8) * 512 + l * 8; \
        _Pragma("unroll")                                                     \
        for (int kk = 0; kk < 8; ++kk)                                        \
            KFN[kk] = *(const half8*)(kb_ + kk * 512);                        \
    }                                                                         \
    /* QK^T: 32 rows x this wave's 16 cols */                                 \
    f32x4 sc0 = (f32x4){0.f,0.f,0.f,0.f}, sc1 = (f32x4){0.f,0.f,0.f,0.f};     \
    _Pragma("unroll")                                                         \
    for (int kk = 0; kk < 8; ++kk) {                                          \
        sc0 = __builtin_amdgcn_mfma_f32_16x16x32_f16(qf0[kk], KFC[kk], sc0, 0, 0, 0); \
        sc1 = __builtin_amdgcn_mfma_f32_16x16x32_f16(qf1[kk], KFC[kk], sc1, 0, 0, 0); \
    }                                                                         \
    /* fixup: p = s * exp(AmM[row] + G[col]), causal mask, fp16 -> swizzled P */ \
    const int gcol = jt * 128 + w * 16 + col;                                 \
    const float gv = sG[gcol];                                                \
    char* pbC = Pb + buf * 8192;                                              \
    const int pcb = (w * 16 + col) * 2;                                       \
    _Pragma("unroll")                                                         \
    for (int rr = 0; rr < 4; ++rr) {                                          \
        const int r0 = quad * 4 + rr;                                         \
        const int sw = (r0 & 7) << 4;                                         \
        float e0 = __expf(amM0[rr] + gv);                                     \
        float p0 = (gcol <= rowbase + r0) ? sc0[rr] * e0 : 0.f;               \
        rs0[rr] += p0;                                                        \
        *(_Float16*)(pbC + r0 * 256 + (pcb ^ sw)) = (_Float16)p0;             \
        float e1 = __expf(amM1[rr] + gv);                                     \
        float p1 = (gcol <= rowbase + 16 + r0) ? sc1[rr] * e1 : 0.f;          \
        rs1[rr] += p1;                                                        \
        *(_Float16*)(pbC + (r0 + 16) * 256 + (pcb ^ sw)) = (_Float16)p1;      \
    }                                                                         \
    /* lgkm-only barrier: P ds ops drained, global prefetches stay in flight */ \
    asm volatile("s_waitcnt lgkmcnt(0)" ::: "memory");                        \
    __builtin_amdgcn_s_barrier();                                             \
    /* PV: A = P[32x128] from swizzled LDS, B = this wave's 32-wide d-slice */ \
    _Pragma("unroll")                                                         \
    for (int rsub = 0; rsub < 2; ++rsub) {                                    \
        const char* base = pbC + (rsub * 16 + col) * 256;                     \
        const int sw2 = (col & 7) << 4;                                       \
        half8 af[4];                                                          \
        _Pragma("unroll")                                                     \
        for (int k0 = 0; k0 < 4; ++k0)                                        \
            af[k0] = *(const half8*)(base + ((k0 * 64 + quad * 16) ^ sw2));   \
        _Pragma("unroll")                                                     \
        for (int k0 = 0; k0 < 4; ++k0) {                                      \
            acc[rsub * 2 + 0] = __builtin_amdgcn_mfma_f32_16x16x32_f16(af[k0], vf[k0],     acc[rsub * 2 + 0], 0, 0, 0); \
            acc[rsub * 2 + 1] = __builtin_amdgcn_mfma_f32_16x16x32_f16(af[k0], vf[4 + k0], acc[rsub * 2 + 1], 0, 0, 0); \
        }                                                                     \
    }                                                                         \
    buf ^= 1;                                                                 \
}

__global__ __launch_bounds__(512, 2) void mlstm_kernel(
    const _Float16* __restrict__ Qh, const _Float16* __restrict__ Kh,
    const _Float16* __restrict__ Vt,
    const float* __restrict__ ig, const float* __restrict__ fg,
    const float* __restrict__ rms_scale, float* __restrict__ out)
{
    __shared__ __align__(16) char SMEM[SMB];
    char*  Pb    = SMEM;                             // [2][32][256 B] halfs, swizzled
    float* sAmM  = (float*)(SMEM + OFF_AMM);         // [S]
    float* sG    = (float*)(SMEM + OFF_G);           // [S]
    float* sM    = (float*)(SMEM + OFF_M);           // [S]
    float* rsumP = (float*)(SMEM + OFF_RS);          // [8][32]
    float* ssP   = (float*)(SMEM + OFF_SS);          // [8][32]
    float* wred  = (float*)(SMEM + OFF_WR);
    float* wred2 = wred + 8;

    const int z  = blockIdx.x;
    const int bh = z & 7;                 // one head per XCD
    const int u  = (z >> 3) & 31;
    const int pass = z >> 8;              // {u, 63-u} split across 2 blocks
    const int b  = bh >> 2, h = bh & 3;
    const int t  = threadIdx.x;
    const int w  = t >> 6;                // 0..7: QK col group (16) / PV d-slice (32)
    const int l  = t & 63;
    const int col  = l & 15;
    const int quad = l >> 4;

    // ---- scan prologue: wave-level shfl scans ----
    {
        const float* fgp = fg + (size_t)bh * S_;
        const float* igp = ig + (size_t)bh * S_;
        float4 fx = *(const float4*)(fgp + t * 4);
        float4 ix = *(const float4*)(igp + t * 4);
        float xi[4] = {fx.x, fx.y, fx.z, fx.w};
        float gi[4] = {ix.x, ix.y, ix.z, ix.w};
        float ls[4];
        float run = 0.f;
        #pragma unroll
        for (int i = 0; i < 4; ++i) {
            float x = xi[i];
            float lg = (x >= 0.f) ? -log1pf(expf(-x)) : (x - log1pf(expf(x)));
            run += lg;
            ls[i] = run;
        }
        const float own = run;
        #pragma unroll
        for (int m = 1; m < 64; m <<= 1) {
            float o = __shfl_up(run, m);
            if (l >= m) run += o;
        }
        if (l == 63) wred[w] = run;
        __syncthreads();
        float wpre = 0.f;
        for (int ww = 0; ww < w; ++ww) wpre += wred[ww];
        const float exclT = wpre + run - own;
        float A[4], g[4], gm[4];
        float rmax = -__builtin_inff();
        #pragma unroll
        for (int i = 0; i < 4; ++i) {
            A[i] = exclT + ls[i];
            g[i] = gi[i] - A[i];
            rmax = fmaxf(rmax, g[i]);
            gm[i] = rmax;
        }
        float sm = rmax;
        #pragma unroll
        for (int m = 1; m < 64; m <<= 1) {
            float o = __shfl_up(sm, m);
            if (l >= m) sm = fmaxf(sm, o);
        }
        if (l == 63) wred2[w] = sm;
        __syncthreads();
        float exm = -__builtin_inff();
        for (int ww = 0; ww < w; ++ww) exm = fmaxf(exm, wred2[ww]);
        float up = __shfl_up(sm, 1);
        if (l > 0) exm = fmaxf(exm, up);
        #pragma unroll
        for (int i = 0; i < 4; ++i) {
            float cm = fmaxf(exm, gm[i]);
            float Mi = A[i] + cm;
            sAmM[t * 4 + i] = A[i] - Mi;
            sG[t * 4 + i]   = g[i];
            sM[t * 4 + i]   = Mi;
        }
        __syncthreads();
    }

    const _Float16* Qp  = Qh + (size_t)bh * S_ * HD_;
    const _Float16* Kp  = Kh + (size_t)bh * S_ * HD_;
    const _Float16* Vtp = Vt + (size_t)bh * HD_ * S_;

    const int rb = pass ? (63 - u) : u;
    const int rowbase = rb * 32;
    const int Tt = (rb >> 2) + 1;          // KVBLK=128 causal tile count

    // Q fragments: both 16-row halves (64 VGPR), reused across all tiles
    half8 qf0[8], qf1[8];
    {
        const _Float16* qb0 = Qp + ((size_t)(rb * 2) * 8) * 512 + l * 8;
        const _Float16* qb1 = Qp + ((size_t)(rb * 2 + 1) * 8) * 512 + l * 8;
        #pragma unroll
        for (int kk = 0; kk < 8; ++kk) {
            qf0[kk] = *(const half8*)(qb0 + kk * 512);
            qf1[kk] = *(const half8*)(qb1 + kk * 512);
        }
    }
    float amM0[4], amM1[4];
    #pragma unroll
    for (int rr = 0; rr < 4; ++rr) {
        amM0[rr] = sAmM[rowbase + quad * 4 + rr];
        amM1[rr] = sAmM[rowbase + 16 + quad * 4 + rr];
    }

    f32x4 acc[4];
    #pragma unroll
    for (int i = 0; i < 4; ++i) acc[i] = (f32x4){0.f, 0.f, 0.f, 0.f};
    float rs0[4] = {0.f,0.f,0.f,0.f}, rs1[4] = {0.f,0.f,0.f,0.f};

    // preload tile-0 K into set 0 (this wave's exclusive 16 K-rows)
    half8 kf0[8], kf1[8], vf[8];
    {
        const _Float16* kb_ = Kp + ((size_t)(w * 8)) * 512 + l * 8;
        #pragma unroll
        for (int kk = 0; kk < 8; ++kk)
            kf0[kk] = *(const half8*)(kb_ + kk * 512);
    }

    int buf = 0;
    int jt = 0;
    while (true) {
        TILE_BODY(kf0, kf1);
        if (++jt >= Tt) break;
        TILE_BODY(kf1, kf0);
        if (++jt >= Tt) break;
    }

    // ---- epilogue: rowsum across 8 col-waves, normalize, RMSNorm, store d-slice ----
    #pragma unroll
    for (int m = 1; m < 16; m <<= 1) {
        #pragma unroll
        for (int rr = 0; rr < 4; ++rr) {
            rs0[rr] += __shfl_xor(rs0[rr], m);
            rs1[rr] += __shfl_xor(rs1[rr], m);
        }
    }
    if (col == 0) {
        #pragma unroll
        for (int rr = 0; rr < 4; ++rr) {
            rsumP[w * 32 + quad * 4 + rr]      = rs0[rr];
            rsumP[w * 32 + 16 + quad * 4 + rr] = rs1[rr];
        }
    }
    __syncthreads();
    float inv0[4], inv1[4];
    #pragma unroll
    for (int rr = 0; rr < 4; ++rr) {
        const int r0 = quad * 4 + rr;
        float tot0 = 0.f, tot1 = 0.f;
        #pragma unroll
        for (int ww = 0; ww < 8; ++ww) {
            tot0 += rsumP[ww * 32 + r0];
            tot1 += rsumP[ww * 32 + 16 + r0];
        }
        float M0 = sM[rowbase + r0];
        float M1 = sM[rowbase + 16 + r0];
        inv0[rr] = 1.0f / (fmaxf(tot0, __expf(-M0)) + 1e-6f);
        inv1[rr] = 1.0f / (fmaxf(tot1, __expf(-M1)) + 1e-6f);
    }
    float ss0[4] = {0.f,0.f,0.f,0.f}, ss1[4] = {0.f,0.f,0.f,0.f};
    #pragma unroll
    for (int dn = 0; dn < 2; ++dn) {
        #pragma unroll
        for (int rr = 0; rr < 4; ++rr) {
            float h0 = acc[dn][rr] * inv0[rr];
            acc[dn][rr] = h0;
            ss0[rr] = fmaf(h0, h0, ss0[rr]);
            float h1 = acc[2 + dn][rr] * inv1[rr];
            acc[2 + dn][rr] = h1;
            ss1[rr] = fmaf(h1, h1, ss1[rr]);
        }
    }
    #pragma unroll
    for (int m = 1; m < 16; m <<= 1) {
        #pragma unroll
        for (int rr = 0; rr < 4; ++rr) {
            ss0[rr] += __shfl_xor(ss0[rr], m);
            ss1[rr] += __shfl_xor(ss1[rr], m);
        }
    }
    if (col == 0) {
        #pragma unroll
        for (int rr = 0; rr < 4; ++rr) {
            ssP[w * 32 + quad * 4 + rr]      = ss0[rr];
            ssP[w * 32 + 16 + quad * 4 + rr] = ss1[rr];
        }
    }
    __syncthreads();
    const float rsc0 = 1.f + rms_scale[w * 32 + col];
    const float rsc1 = 1.f + rms_scale[w * 32 + 16 + col];
    #pragma unroll
    for (int rr = 0; rr < 4; ++rr) {
        const int r0 = quad * 4 + rr;
        float sst0 = 0.f, sst1 = 0.f;
        #pragma unroll
        for (int ww = 0; ww < 8; ++ww) {
            sst0 += ssP[ww * 32 + r0];
            sst1 += ssP[ww * 32 + 16 + r0];
        }
        float rstd0 = rsqrtf(sst0 * (1.0f / HD_) + 1e-6f);
        float rstd1 = rsqrtf(sst1 * (1.0f / HD_) + 1e-6f);
        float* o0 = out + ((size_t)(b * S_ + rowbase + r0)) * E_ + h * HD_ + w * 32;
        float* o1 = out + ((size_t)(b * S_ + rowbase + 16 + r0)) * E_ + h * HD_ + w * 32;
        o0[col]      = acc[0][rr] * rstd0 * rsc0;
        o0[16 + col] = acc[1][rr] * rstd0 * rsc1;
        o1[col]      = acc[2][rr] * rstd1 * rsc0;
        o1[16 + col] = acc[3][rr] * rstd1 * rsc1;
    }
}

extern "C" void kernel_launch(void* const* d_in, const int* in_sizes, int n_in,
                              void* d_out, int out_size, void* d_ws, size_t ws_size,
                              hipStream_t stream) {
    (void)in_sizes; (void)n_in; (void)out_size; (void)ws_size;
    const float* q   = (const float*)d_in[0];
    const float* k   = (const float*)d_in[1];
    const float* v   = (const float*)d_in[2];
    const float* igk = (const float*)d_in[3];
    const float* igb = (const float*)d_in[4];
    const float* fgk = (const float*)d_in[5];
    const float* fgb = (const float*)d_in[6];
    const float* rsc = (const float*)d_in[7];
    float* out = (float*)d_out;

    float* ws  = (float*)d_ws;
    float* ig  = ws;                          // BH*S each
    float* fg  = ws + (size_t)BH_ * S_;
    _Float16* Qh = (_Float16*)(ws + (size_t)2 * BH_ * S_);
    _Float16* Kh = Qh + (size_t)BH_ * S_ * HD_;
    _Float16* Vt = Kh + (size_t)BH_ * S_ * HD_;

    prep_kernel<<<B_ * S_ / 16, 1024, 0, stream>>>(q, k, v, igk, igb, fgk, fgb,
                                                   ig, fg, Qh, Kh, Vt);
    mlstm_kernel<<<BH_ * 64, 512, 0, stream>>>(Qh, Kh, Vt, ig, fg, rsc, out);
}